// Round 3
// baseline (674.446 us; speedup 1.0000x reference)
//
#include <hip/hip_runtime.h>
#include <hip/hip_bf16.h>

typedef __bf16 bf16_t;
typedef bf16_t bf16x8 __attribute__((ext_vector_type(8)));
typedef bf16_t bf16x4 __attribute__((ext_vector_type(4)));
typedef float f32x4 __attribute__((ext_vector_type(4)));

#define H 256
#define SEQ 4096
#define BSZ 32
#define T_TOK 32          // tokens per block
#define HROWS 48          // hbf allocated rows (3 m-tiles of 16)
#define A_ROWS 34         // valid token rows: t0-1 .. t0+32
#define B_ROWS 33
#define S_ROWS 32
#define LSTR 264          // uniform row stride (+8 pad = +4 banks per row)

// LDS layout (bf16 element offsets) — total 38808 elems = 77616 B -> 2 blocks/CU
#define OFF_HBF 0
#define OFF_A   (HROWS * LSTR)                 // 12672
#define OFF_B   (OFF_A + A_ROWS * LSTR)        // 21648
#define OFF_S   (OFF_B + B_ROWS * LSTR)        // 30360
#define SMEM_ELEMS (OFF_S + S_ROWS * LSTR)     // 38808
#define SMEM_BYTES (SMEM_ELEMS * 2)
#define OFF_AGG OFF_A                          // aliases A (dead after S-pass)
#define OFF_HN  OFF_B                          // aliases B (dead after S-pass)

// ws layout (bf16 element offsets): transposed weights W^T[n][k]
#define WABT  0           // [512][256]
#define W2T   131072      // [256][256]
#define WN1AT 196608
#define WN1BT 262144
#define WN2T  327680
#define WS_ELEMS 393216

// ---- prepass: f32 weights -> bf16 transposed in ws ----
__global__ void wprep(const float* __restrict__ ew1, const float* __restrict__ ew2,
                      const float* __restrict__ nw1, const float* __restrict__ nw2,
                      bf16_t* __restrict__ wsw) {
    int idx = blockIdx.x * 256 + threadIdx.x;
    float v;
    if (idx < W2T) {
        int n = idx >> 8, k = idx & 255;
        v = (n < 256) ? ew1[k * 256 + n] : ew1[(256 + k) * 256 + (n - 256)];
    } else if (idx < WN1AT) {
        int r = idx - W2T; int n = r >> 8, k = r & 255;
        v = ew2[k * 256 + n];
    } else if (idx < WN1BT) {
        int r = idx - WN1AT; int n = r >> 8, k = r & 255;
        v = nw1[k * 256 + n];
    } else if (idx < WN2T) {
        int r = idx - WN1BT; int n = r >> 8, k = r & 255;
        v = nw1[(256 + k) * 256 + n];
    } else {
        int r = idx - WN2T; int n = r >> 8, k = r & 255;
        v = nw2[k * 256 + n];
    }
    wsw[idx] = (bf16_t)v;
}

// ---- fused GraphNet layer ----
// MFMA: A-operand = weight frag (C rows = features), B-operand = activation
// (C cols = tokens). Lane holds token lane&15, features crb..crb+3 -> b64 write.
__launch_bounds__(512, 4)
__global__ void gnl_kernel(const float* __restrict__ h, const float* __restrict__ mask,
                           const float* __restrict__ eb1, const float* __restrict__ eb2,
                           const float* __restrict__ nb1, const float* __restrict__ nb2,
                           const bf16_t* __restrict__ wsw, float* __restrict__ out) {
    extern __shared__ bf16_t sm[];
    bf16_t* hbf = sm + OFF_HBF;   // [HROWS][LSTR], row r <-> token t0-1+r
    bf16_t* Ab  = sm + OFF_A;     // [A_ROWS][LSTR]  x@w1a per token row
    bf16_t* Bb  = sm + OFF_B;     // [B_ROWS][LSTR]  x@w1b per token row
    bf16_t* S   = sm + OFF_S;     // [S_ROWS][LSTR]
    bf16_t* AGG = sm + OFF_AGG;   // aliases A
    bf16_t* HN  = sm + OFF_HN;    // aliases B

    const int tid   = threadIdx.x;
    const int lane  = tid & 63;
    const int w     = tid >> 6;            // wave 0..7
    const int batch = blockIdx.x >> 7;
    const int tile  = blockIdx.x & 127;
    const int t0    = tile * T_TOK;
    const long baseTok = (long)batch * SEQ;

    const int lr  = lane & 15;             // token-in-tile (C col) / weight row
    const int lk  = (lane >> 4) << 3;      // k offset {0,8,16,24}
    const int crb = (lane >> 4) << 2;      // feature base {0,4,8,12}

    // ---- preload phase-1 weight frags (overlaps staging) ----
    bf16x8 wf1[4][8];
#pragma unroll
    for (int i = 0; i < 4; ++i) {
        const bf16_t* wb = wsw + WABT + ((((w << 2) + i) * 16 + lr) << 8) + lk;
#pragma unroll
        for (int ks = 0; ks < 8; ++ks) wf1[i][ks] = *(const bf16x8*)(wb + (ks << 5));
    }

    // ---------- Phase 0: stage h -> bf16 LDS (zero-padded) ----------
#pragma unroll
    for (int it = 0; it < 3; ++it) {
        int c = tid + it * 512;            // 48*32 = 1536 chunks exactly
        int r = c >> 5;
        int fc = (c & 31) << 3;
        int t = t0 - 1 + r;
        bf16x8 vals;
        if (r < A_ROWS && t >= 0 && t < SEQ) {
            const float* src = h + (((long)(baseTok + t)) << 8) + fc;
            float4 x0 = ((const float4*)src)[0];
            float4 x1 = ((const float4*)src)[1];
            vals[0] = (bf16_t)x0.x; vals[1] = (bf16_t)x0.y;
            vals[2] = (bf16_t)x0.z; vals[3] = (bf16_t)x0.w;
            vals[4] = (bf16_t)x1.x; vals[5] = (bf16_t)x1.y;
            vals[6] = (bf16_t)x1.z; vals[7] = (bf16_t)x1.w;
        } else {
#pragma unroll
            for (int j = 0; j < 8; ++j) vals[j] = (bf16_t)0.0f;
        }
        *(bf16x8*)(hbf + r * LSTR + fc) = vals;
    }
    __syncthreads();

    // ---------- Phase 1: [A|B] = hbf @ [w1a|w1b]  (N = 512) ----------
#pragma unroll
    for (int mt = 0; mt < 3; ++mt) {
        bf16x8 hf[8];
        const bf16_t* pa = hbf + (mt * 16 + lr) * LSTR + lk;
#pragma unroll
        for (int ks = 0; ks < 8; ++ks) hf[ks] = *(const bf16x8*)(pa + (ks << 5));
        int row = mt * 16 + lr;            // token row of this lane's C col
#pragma unroll
        for (int i = 0; i < 4; ++i) {
            int nt = (w << 2) + i;
            f32x4 acc = {0.f, 0.f, 0.f, 0.f};
            __builtin_amdgcn_s_setprio(1);
#pragma unroll
            for (int ks = 0; ks < 8; ++ks)
                acc = __builtin_amdgcn_mfma_f32_16x16x32_bf16(wf1[i][ks], hf[ks], acc, 0, 0, 0);
            __builtin_amdgcn_s_setprio(0);
            bf16x4 pv;
#pragma unroll
            for (int j = 0; j < 4; ++j) pv[j] = (bf16_t)acc[j];
            if (nt < 16) {
                if (row < A_ROWS)
                    *(bf16x4*)(Ab + row * LSTR + nt * 16 + crb) = pv;
            } else {
                if (row < B_ROWS)
                    *(bf16x4*)(Bb + row * LSTR + (nt - 16) * 16 + crb) = pv;
            }
        }
    }
    __syncthreads();

    // ---- preload phase-2 weight frags ----
    bf16x8 wf2[2][8];
#pragma unroll
    for (int i = 0; i < 2; ++i) {
        const bf16_t* wb = wsw + W2T + ((((w << 1) + i) * 16 + lr) << 8) + lk;
#pragma unroll
        for (int ks = 0; ks < 8; ++ks) wf2[i][ks] = *(const bf16x8*)(wb + (ks << 5));
    }

    // ---------- S pass: S[i] = relu(A[i]+B[i+1]+b1)*L + relu(A[i+2]+B[i+1]+b1)*R ----------
#pragma unroll
    for (int it = 0; it < 2; ++it) {
        int c = tid + it * 512;            // 32*32 = 1024 chunks exactly
        int i = c >> 5;
        int fc = (c & 31) << 3;
        int t = t0 + i;
        float bl = (t >= 1) ? 1.f : 0.f;
        float br = (t <= SEQ - 2) ? 1.f : 0.f;
        bf16x8 aL = *(const bf16x8*)(Ab + i * LSTR + fc);
        bf16x8 aR = *(const bf16x8*)(Ab + (i + 2) * LSTR + fc);
        bf16x8 bC = *(const bf16x8*)(Bb + (i + 1) * LSTR + fc);
        float4 b1a = *(const float4*)(eb1 + fc);
        float4 b1b = *(const float4*)(eb1 + fc + 4);
        bf16x8 sv;
#pragma unroll
        for (int j = 0; j < 8; ++j) {
            float b1f = (j < 4) ? ((const float*)&b1a)[j] : ((const float*)&b1b)[j - 4];
            float x = (float)bC[j] + b1f;
            float l = fmaxf((float)aL[j] + x, 0.f) * bl;
            float r = fmaxf((float)aR[j] + x, 0.f) * br;
            sv[j] = (bf16_t)(l + r);
        }
        *(bf16x8*)(S + i * LSTR + fc) = sv;
    }
    __syncthreads();

    // ---------- Phase 2: AGG = S @ w2 + cnt*b2 ----------
#pragma unroll
    for (int mt = 0; mt < 2; ++mt) {
        bf16x8 sf[8];
        const bf16_t* pa = S + (mt * 16 + lr) * LSTR + lk;
#pragma unroll
        for (int ks = 0; ks < 8; ++ks) sf[ks] = *(const bf16x8*)(pa + (ks << 5));
        int t = t0 + mt * 16 + lr;
        float cnt = ((t >= 1) ? 1.f : 0.f) + ((t <= SEQ - 2) ? 1.f : 0.f);
#pragma unroll
        for (int i = 0; i < 2; ++i) {
            f32x4 acc = {0.f, 0.f, 0.f, 0.f};
            __builtin_amdgcn_s_setprio(1);
#pragma unroll
            for (int ks = 0; ks < 8; ++ks)
                acc = __builtin_amdgcn_mfma_f32_16x16x32_bf16(wf2[i][ks], sf[ks], acc, 0, 0, 0);
            __builtin_amdgcn_s_setprio(0);
            int n0 = ((w << 1) + i) * 16;
            float4 b2v = *(const float4*)(eb2 + n0 + crb);
            bf16x4 pv;
#pragma unroll
            for (int j = 0; j < 4; ++j)
                pv[j] = (bf16_t)(acc[j] + cnt * ((const float*)&b2v)[j]);
            *(bf16x4*)(AGG + (mt * 16 + lr) * LSTR + n0 + crb) = pv;
        }
    }
    __syncthreads();

    // ---------- Phase 3: HN = relu(h @ nw1a + AGG @ nw1b + nb1) ----------
    {
        f32x4 acc3[2][2];
#pragma unroll
        for (int mt = 0; mt < 2; ++mt)
#pragma unroll
            for (int i = 0; i < 2; ++i) acc3[mt][i] = f32x4{0.f, 0.f, 0.f, 0.f};

        bf16x8 wfa[2][8];
#pragma unroll
        for (int i = 0; i < 2; ++i) {
            const bf16_t* wb = wsw + WN1AT + ((((w << 1) + i) * 16 + lr) << 8) + lk;
#pragma unroll
            for (int ks = 0; ks < 8; ++ks) wfa[i][ks] = *(const bf16x8*)(wb + (ks << 5));
        }
#pragma unroll
        for (int mt = 0; mt < 2; ++mt) {
            bf16x8 hf[8];
            const bf16_t* ph = hbf + (mt * 16 + 1 + lr) * LSTR + lk;
#pragma unroll
            for (int ks = 0; ks < 8; ++ks) hf[ks] = *(const bf16x8*)(ph + (ks << 5));
            __builtin_amdgcn_s_setprio(1);
#pragma unroll
            for (int i = 0; i < 2; ++i)
#pragma unroll
                for (int ks = 0; ks < 8; ++ks)
                    acc3[mt][i] = __builtin_amdgcn_mfma_f32_16x16x32_bf16(wfa[i][ks], hf[ks], acc3[mt][i], 0, 0, 0);
            __builtin_amdgcn_s_setprio(0);
        }
#pragma unroll
        for (int i = 0; i < 2; ++i) {
            const bf16_t* wb = wsw + WN1BT + ((((w << 1) + i) * 16 + lr) << 8) + lk;
#pragma unroll
            for (int ks = 0; ks < 8; ++ks) wfa[i][ks] = *(const bf16x8*)(wb + (ks << 5));
        }
#pragma unroll
        for (int mt = 0; mt < 2; ++mt) {
            bf16x8 gf[8];
            const bf16_t* pg = AGG + (mt * 16 + lr) * LSTR + lk;
#pragma unroll
            for (int ks = 0; ks < 8; ++ks) gf[ks] = *(const bf16x8*)(pg + (ks << 5));
            __builtin_amdgcn_s_setprio(1);
#pragma unroll
            for (int i = 0; i < 2; ++i)
#pragma unroll
                for (int ks = 0; ks < 8; ++ks)
                    acc3[mt][i] = __builtin_amdgcn_mfma_f32_16x16x32_bf16(wfa[i][ks], gf[ks], acc3[mt][i], 0, 0, 0);
            __builtin_amdgcn_s_setprio(0);
        }
        __syncthreads();   // AGG consumed; HN region (aliases B) free to write
#pragma unroll
        for (int mt = 0; mt < 2; ++mt)
#pragma unroll
            for (int i = 0; i < 2; ++i) {
                int n0 = ((w << 1) + i) * 16;
                float4 nb14 = *(const float4*)(nb1 + n0 + crb);
                bf16x4 pv;
#pragma unroll
                for (int j = 0; j < 4; ++j)
                    pv[j] = (bf16_t)fmaxf(acc3[mt][i][j] + ((const float*)&nb14)[j], 0.f);
                *(bf16x4*)(HN + (mt * 16 + lr) * LSTR + n0 + crb) = pv;
            }
    }
    __syncthreads();

    // ---------- Phase 4: out = h + mask * (HN @ nw2 + nb2) ----------
    {
        bf16x8 wf4[2][8];
#pragma unroll
        for (int i = 0; i < 2; ++i) {
            const bf16_t* wb = wsw + WN2T + ((((w << 1) + i) * 16 + lr) << 8) + lk;
#pragma unroll
            for (int ks = 0; ks < 8; ++ks) wf4[i][ks] = *(const bf16x8*)(wb + (ks << 5));
        }
#pragma unroll
        for (int mt = 0; mt < 2; ++mt) {
            bf16x8 hnf[8];
            const bf16_t* pa = HN + (mt * 16 + lr) * LSTR + lk;
#pragma unroll
            for (int ks = 0; ks < 8; ++ks) hnf[ks] = *(const bf16x8*)(pa + (ks << 5));
            long t = baseTok + t0 + mt * 16 + lr;
            float m = mask[t];
#pragma unroll
            for (int i = 0; i < 2; ++i) {
                f32x4 acc = {0.f, 0.f, 0.f, 0.f};
                __builtin_amdgcn_s_setprio(1);
#pragma unroll
                for (int ks = 0; ks < 8; ++ks)
                    acc = __builtin_amdgcn_mfma_f32_16x16x32_bf16(wf4[i][ks], hnf[ks], acc, 0, 0, 0);
                __builtin_amdgcn_s_setprio(0);
                int n0 = ((w << 1) + i) * 16;
                float4 nb24 = *(const float4*)(nb2 + n0 + crb);
                long gaddr = (t << 8) + n0 + crb;
                float4 h4 = *(const float4*)(h + gaddr);
                float4 o;
                o.x = h4.x + m * (acc[0] + nb24.x);
                o.y = h4.y + m * (acc[1] + nb24.y);
                o.z = h4.z + m * (acc[2] + nb24.z);
                o.w = h4.w + m * (acc[3] + nb24.w);
                *(float4*)(out + gaddr) = o;
            }
        }
    }
}

extern "C" void kernel_launch(void* const* d_in, const int* in_sizes, int n_in,
                              void* d_out, int out_size, void* d_ws, size_t ws_size,
                              hipStream_t stream) {
    const float* h    = (const float*)d_in[0];
    const float* mask = (const float*)d_in[1];
    const float* ew1  = (const float*)d_in[2];
    const float* eb1  = (const float*)d_in[3];
    const float* ew2  = (const float*)d_in[4];
    const float* eb2  = (const float*)d_in[5];
    const float* nw1  = (const float*)d_in[6];
    const float* nb1  = (const float*)d_in[7];
    const float* nw2  = (const float*)d_in[8];
    const float* nb2  = (const float*)d_in[9];
    float* out   = (float*)d_out;
    bf16_t* wsw  = (bf16_t*)d_ws;

    wprep<<<WS_ELEMS / 256, 256, 0, stream>>>(ew1, ew2, nw1, nw2, wsw);

    hipFuncSetAttribute(reinterpret_cast<const void*>(gnl_kernel),
                        hipFuncAttributeMaxDynamicSharedMemorySize, SMEM_BYTES);

    gnl_kernel<<<BSZ * (SEQ / T_TOK), 512, SMEM_BYTES, stream>>>(
        h, mask, eb1, eb2, nb1, nb2, wsw, out);
}

// Round 4
// 398.404 us; speedup vs baseline: 1.6929x; 1.6929x over previous
//
#include <hip/hip_runtime.h>
#include <hip/hip_bf16.h>

typedef __bf16 bf16_t;
typedef bf16_t bf16x8 __attribute__((ext_vector_type(8)));
typedef bf16_t bf16x4 __attribute__((ext_vector_type(4)));
typedef float f32x4 __attribute__((ext_vector_type(4)));

#define H 256
#define SEQ 4096
#define BSZ 32
#define T_TOK 32          // tokens per block
#define HROWS 48          // hbf allocated rows (3 m-tiles of 16)
#define A_ROWS 34         // valid token rows: t0-1 .. t0+32
#define B_ROWS 33
#define S_ROWS 32
#define LSTR 264          // uniform row stride (+8 pad)

// LDS layout (bf16 element offsets) — total 38808 elems = 77616 B -> 2 blocks/CU
#define OFF_HBF 0
#define OFF_A   (HROWS * LSTR)                 // 12672
#define OFF_B   (OFF_A + A_ROWS * LSTR)        // 21648
#define OFF_S   (OFF_B + B_ROWS * LSTR)        // 30360
#define SMEM_ELEMS (OFF_S + S_ROWS * LSTR)     // 38808
#define SMEM_BYTES (SMEM_ELEMS * 2)            // 77616
#define OFF_AGG OFF_A                          // aliases A (dead after S-pass)
#define OFF_HN  OFF_B                          // aliases B (dead after S-pass)

// ws layout (bf16 element offsets): transposed weights W^T[n][k]
#define WABT  0           // [512][256]
#define W2T   131072      // [256][256]
#define WN1AT 196608
#define WN1BT 262144
#define WN2T  327680
#define WS_ELEMS 393216

// ---- prepass: f32 weights -> bf16 transposed in ws ----
__global__ void wprep(const float* __restrict__ ew1, const float* __restrict__ ew2,
                      const float* __restrict__ nw1, const float* __restrict__ nw2,
                      bf16_t* __restrict__ wsw) {
    int idx = blockIdx.x * 256 + threadIdx.x;
    float v;
    if (idx < W2T) {
        int n = idx >> 8, k = idx & 255;
        v = (n < 256) ? ew1[k * 256 + n] : ew1[(256 + k) * 256 + (n - 256)];
    } else if (idx < WN1AT) {
        int r = idx - W2T; int n = r >> 8, k = r & 255;
        v = ew2[k * 256 + n];
    } else if (idx < WN1BT) {
        int r = idx - WN1AT; int n = r >> 8, k = r & 255;
        v = nw1[k * 256 + n];
    } else if (idx < WN2T) {
        int r = idx - WN1BT; int n = r >> 8, k = r & 255;
        v = nw1[(256 + k) * 256 + n];
    } else {
        int r = idx - WN2T; int n = r >> 8, k = r & 255;
        v = nw2[k * 256 + n];
    }
    wsw[idx] = (bf16_t)v;
}

// ---- fused GraphNet layer ----
// MFMA: A-operand = weight frag (C rows = features), B-operand = activation
// (C cols = tokens). Lane holds token lane&15, features crb..crb+3 -> b64 write.
// Register discipline (R3 lesson): never hold more than ONE n-tile's weight
// fragments (32 VGPRs) live — loop-local loads, no big preloads.
__launch_bounds__(512, 4)
__global__ void gnl_kernel(const float* __restrict__ h, const float* __restrict__ mask,
                           const float* __restrict__ eb1, const float* __restrict__ eb2,
                           const float* __restrict__ nb1, const float* __restrict__ nb2,
                           const bf16_t* __restrict__ wsw, float* __restrict__ out) {
    extern __shared__ bf16_t sm[];
    bf16_t* hbf = sm + OFF_HBF;   // [HROWS][LSTR], row r <-> token t0-1+r
    bf16_t* Ab  = sm + OFF_A;     // [A_ROWS][LSTR]  x@w1a per token row
    bf16_t* Bb  = sm + OFF_B;     // [B_ROWS][LSTR]  x@w1b per token row
    bf16_t* S   = sm + OFF_S;     // [S_ROWS][LSTR]
    bf16_t* AGG = sm + OFF_AGG;   // aliases A
    bf16_t* HN  = sm + OFF_HN;    // aliases B

    const int tid   = threadIdx.x;
    const int lane  = tid & 63;
    const int w     = tid >> 6;            // wave 0..7
    const int batch = blockIdx.x >> 7;
    const int tile  = blockIdx.x & 127;
    const int t0    = tile * T_TOK;
    const long baseTok = (long)batch * SEQ;

    const int lr  = lane & 15;             // token-in-tile (C col) / weight row
    const int lk  = (lane >> 4) << 3;      // k offset {0,8,16,24}
    const int crb = (lane >> 4) << 2;      // feature base {0,4,8,12}

    // ---------- Phase 0: stage h -> bf16 LDS (zero-padded) ----------
#pragma unroll
    for (int it = 0; it < 3; ++it) {
        int c = tid + it * 512;            // 48*32 = 1536 chunks exactly
        int r = c >> 5;
        int fc = (c & 31) << 3;
        int t = t0 - 1 + r;
        bf16x8 vals;
        if (r < A_ROWS && t >= 0 && t < SEQ) {
            const float* src = h + (((long)(baseTok + t)) << 8) + fc;
            float4 x0 = ((const float4*)src)[0];
            float4 x1 = ((const float4*)src)[1];
            vals[0] = (bf16_t)x0.x; vals[1] = (bf16_t)x0.y;
            vals[2] = (bf16_t)x0.z; vals[3] = (bf16_t)x0.w;
            vals[4] = (bf16_t)x1.x; vals[5] = (bf16_t)x1.y;
            vals[6] = (bf16_t)x1.z; vals[7] = (bf16_t)x1.w;
        } else {
#pragma unroll
            for (int j = 0; j < 8; ++j) vals[j] = (bf16_t)0.0f;
        }
        *(bf16x8*)(hbf + r * LSTR + fc) = vals;
    }
    __syncthreads();

    // ---------- Phase 1: [A|B] = hbf @ [w1a|w1b]  (N = 512) ----------
    // weights outer (one n-tile's frags live), activations inner (LDS re-read)
#pragma unroll
    for (int i = 0; i < 4; ++i) {
        int nt = (w << 2) + i;
        bf16x8 bfr[8];
        const bf16_t* wb = wsw + WABT + ((nt * 16 + lr) << 8) + lk;
#pragma unroll
        for (int ks = 0; ks < 8; ++ks) bfr[ks] = *(const bf16x8*)(wb + (ks << 5));
#pragma unroll
        for (int mt = 0; mt < 3; ++mt) {
            bf16x8 hf[8];
            const bf16_t* pa = hbf + (mt * 16 + lr) * LSTR + lk;
#pragma unroll
            for (int ks = 0; ks < 8; ++ks) hf[ks] = *(const bf16x8*)(pa + (ks << 5));
            f32x4 acc = {0.f, 0.f, 0.f, 0.f};
            __builtin_amdgcn_s_setprio(1);
#pragma unroll
            for (int ks = 0; ks < 8; ++ks)
                acc = __builtin_amdgcn_mfma_f32_16x16x32_bf16(bfr[ks], hf[ks], acc, 0, 0, 0);
            __builtin_amdgcn_s_setprio(0);
            int row = mt * 16 + lr;
            bf16x4 pv;
#pragma unroll
            for (int j = 0; j < 4; ++j) pv[j] = (bf16_t)acc[j];
            if (nt < 16) {
                if (row < A_ROWS)
                    *(bf16x4*)(Ab + row * LSTR + nt * 16 + crb) = pv;
            } else {
                if (row < B_ROWS)
                    *(bf16x4*)(Bb + row * LSTR + (nt - 16) * 16 + crb) = pv;
            }
        }
    }
    __syncthreads();

    // ---------- S pass: S[i] = relu(A[i]+B[i+1]+b1)*L + relu(A[i+2]+B[i+1]+b1)*R ----------
#pragma unroll
    for (int it = 0; it < 2; ++it) {
        int c = tid + it * 512;            // 32*32 = 1024 chunks exactly
        int i = c >> 5;
        int fc = (c & 31) << 3;
        int t = t0 + i;
        float bl = (t >= 1) ? 1.f : 0.f;
        float br = (t <= SEQ - 2) ? 1.f : 0.f;
        bf16x8 aL = *(const bf16x8*)(Ab + i * LSTR + fc);
        bf16x8 aR = *(const bf16x8*)(Ab + (i + 2) * LSTR + fc);
        bf16x8 bC = *(const bf16x8*)(Bb + (i + 1) * LSTR + fc);
        float4 b1a = *(const float4*)(eb1 + fc);
        float4 b1b = *(const float4*)(eb1 + fc + 4);
        bf16x8 sv;
#pragma unroll
        for (int j = 0; j < 8; ++j) {
            float b1f = (j < 4) ? ((const float*)&b1a)[j] : ((const float*)&b1b)[j - 4];
            float x = (float)bC[j] + b1f;
            float l = fmaxf((float)aL[j] + x, 0.f) * bl;
            float r = fmaxf((float)aR[j] + x, 0.f) * br;
            sv[j] = (bf16_t)(l + r);
        }
        *(bf16x8*)(S + i * LSTR + fc) = sv;
    }
    __syncthreads();

    // ---------- Phase 2: AGG = S @ w2 + cnt*b2 ----------
#pragma unroll
    for (int i = 0; i < 2; ++i) {
        int n0 = ((w << 1) + i) * 16;
        bf16x8 bfr[8];
        const bf16_t* wb = wsw + W2T + ((n0 + lr) << 8) + lk;
#pragma unroll
        for (int ks = 0; ks < 8; ++ks) bfr[ks] = *(const bf16x8*)(wb + (ks << 5));
        float4 b2v = *(const float4*)(eb2 + n0 + crb);
#pragma unroll
        for (int mt = 0; mt < 2; ++mt) {
            bf16x8 sf[8];
            const bf16_t* pa = S + (mt * 16 + lr) * LSTR + lk;
#pragma unroll
            for (int ks = 0; ks < 8; ++ks) sf[ks] = *(const bf16x8*)(pa + (ks << 5));
            f32x4 acc = {0.f, 0.f, 0.f, 0.f};
            __builtin_amdgcn_s_setprio(1);
#pragma unroll
            for (int ks = 0; ks < 8; ++ks)
                acc = __builtin_amdgcn_mfma_f32_16x16x32_bf16(bfr[ks], sf[ks], acc, 0, 0, 0);
            __builtin_amdgcn_s_setprio(0);
            int row = mt * 16 + lr;
            int t = t0 + row;
            float cnt = ((t >= 1) ? 1.f : 0.f) + ((t <= SEQ - 2) ? 1.f : 0.f);
            bf16x4 pv;
#pragma unroll
            for (int j = 0; j < 4; ++j)
                pv[j] = (bf16_t)(acc[j] + cnt * ((const float*)&b2v)[j]);
            *(bf16x4*)(AGG + row * LSTR + n0 + crb) = pv;
        }
    }
    __syncthreads();

    // ---------- Phase 3: HN = relu(h @ nw1a + AGG @ nw1b + nb1) ----------
    {
        f32x4 acc3[2][2];   // [mt][i], persists across both K-halves
#pragma unroll
        for (int mt = 0; mt < 2; ++mt)
#pragma unroll
            for (int i = 0; i < 2; ++i) acc3[mt][i] = f32x4{0.f, 0.f, 0.f, 0.f};

        // K-half 1: h @ nw1a
#pragma unroll
        for (int i = 0; i < 2; ++i) {
            bf16x8 wfa[8];
            const bf16_t* wb = wsw + WN1AT + ((((w << 1) + i) * 16 + lr) << 8) + lk;
#pragma unroll
            for (int ks = 0; ks < 8; ++ks) wfa[ks] = *(const bf16x8*)(wb + (ks << 5));
#pragma unroll
            for (int mt = 0; mt < 2; ++mt) {
                bf16x8 hf[8];
                const bf16_t* ph = hbf + (mt * 16 + 1 + lr) * LSTR + lk;
#pragma unroll
                for (int ks = 0; ks < 8; ++ks) hf[ks] = *(const bf16x8*)(ph + (ks << 5));
                __builtin_amdgcn_s_setprio(1);
#pragma unroll
                for (int ks = 0; ks < 8; ++ks)
                    acc3[mt][i] = __builtin_amdgcn_mfma_f32_16x16x32_bf16(wfa[ks], hf[ks], acc3[mt][i], 0, 0, 0);
                __builtin_amdgcn_s_setprio(0);
            }
        }
        // K-half 2: AGG @ nw1b
#pragma unroll
        for (int i = 0; i < 2; ++i) {
            bf16x8 wfb[8];
            const bf16_t* wb = wsw + WN1BT + ((((w << 1) + i) * 16 + lr) << 8) + lk;
#pragma unroll
            for (int ks = 0; ks < 8; ++ks) wfb[ks] = *(const bf16x8*)(wb + (ks << 5));
#pragma unroll
            for (int mt = 0; mt < 2; ++mt) {
                bf16x8 gf[8];
                const bf16_t* pg = AGG + (mt * 16 + lr) * LSTR + lk;
#pragma unroll
                for (int ks = 0; ks < 8; ++ks) gf[ks] = *(const bf16x8*)(pg + (ks << 5));
                __builtin_amdgcn_s_setprio(1);
#pragma unroll
                for (int ks = 0; ks < 8; ++ks)
                    acc3[mt][i] = __builtin_amdgcn_mfma_f32_16x16x32_bf16(wfb[ks], gf[ks], acc3[mt][i], 0, 0, 0);
                __builtin_amdgcn_s_setprio(0);
            }
        }
        // epilogue: relu + bias -> HN (aliases dead Bb; no hazard, no barrier needed)
#pragma unroll
        for (int mt = 0; mt < 2; ++mt)
#pragma unroll
            for (int i = 0; i < 2; ++i) {
                int n0 = ((w << 1) + i) * 16;
                float4 nb14 = *(const float4*)(nb1 + n0 + crb);
                bf16x4 pv;
#pragma unroll
                for (int j = 0; j < 4; ++j)
                    pv[j] = (bf16_t)fmaxf(acc3[mt][i][j] + ((const float*)&nb14)[j], 0.f);
                *(bf16x4*)(HN + (mt * 16 + lr) * LSTR + n0 + crb) = pv;
            }
    }
    __syncthreads();

    // ---------- Phase 4: out = h + mask * (HN @ nw2 + nb2) ----------
#pragma unroll
    for (int i = 0; i < 2; ++i) {
        int n0 = ((w << 1) + i) * 16;
        bf16x8 bfr[8];
        const bf16_t* wb = wsw + WN2T + ((n0 + lr) << 8) + lk;
#pragma unroll
        for (int ks = 0; ks < 8; ++ks) bfr[ks] = *(const bf16x8*)(wb + (ks << 5));
        float4 nb24 = *(const float4*)(nb2 + n0 + crb);
#pragma unroll
        for (int mt = 0; mt < 2; ++mt) {
            bf16x8 hnf[8];
            const bf16_t* pa = HN + (mt * 16 + lr) * LSTR + lk;
#pragma unroll
            for (int ks = 0; ks < 8; ++ks) hnf[ks] = *(const bf16x8*)(pa + (ks << 5));
            f32x4 acc = {0.f, 0.f, 0.f, 0.f};
            __builtin_amdgcn_s_setprio(1);
#pragma unroll
            for (int ks = 0; ks < 8; ++ks)
                acc = __builtin_amdgcn_mfma_f32_16x16x32_bf16(bfr[ks], hnf[ks], acc, 0, 0, 0);
            __builtin_amdgcn_s_setprio(0);
            long t = baseTok + t0 + mt * 16 + lr;
            float m = mask[t];
            long gaddr = (t << 8) + n0 + crb;
            float4 h4 = *(const float4*)(h + gaddr);
            float4 o;
            o.x = h4.x + m * (acc[0] + nb24.x);
            o.y = h4.y + m * (acc[1] + nb24.y);
            o.z = h4.z + m * (acc[2] + nb24.z);
            o.w = h4.w + m * (acc[3] + nb24.w);
            *(float4*)(out + gaddr) = o;
        }
    }
}

extern "C" void kernel_launch(void* const* d_in, const int* in_sizes, int n_in,
                              void* d_out, int out_size, void* d_ws, size_t ws_size,
                              hipStream_t stream) {
    const float* h    = (const float*)d_in[0];
    const float* mask = (const float*)d_in[1];
    const float* ew1  = (const float*)d_in[2];
    const float* eb1  = (const float*)d_in[3];
    const float* ew2  = (const float*)d_in[4];
    const float* eb2  = (const float*)d_in[5];
    const float* nw1  = (const float*)d_in[6];
    const float* nb1  = (const float*)d_in[7];
    const float* nw2  = (const float*)d_in[8];
    const float* nb2  = (const float*)d_in[9];
    float* out   = (float*)d_out;
    bf16_t* wsw  = (bf16_t*)d_ws;

    wprep<<<WS_ELEMS / 256, 256, 0, stream>>>(ew1, ew2, nw1, nw2, wsw);

    hipFuncSetAttribute(reinterpret_cast<const void*>(gnl_kernel),
                        hipFuncAttributeMaxDynamicSharedMemorySize, SMEM_BYTES);

    gnl_kernel<<<BSZ * (SEQ / T_TOK), 512, SMEM_BYTES, stream>>>(
        h, mask, eb1, eb2, nb1, nb2, wsw, out);
}

// Round 5
// 171.184 us; speedup vs baseline: 3.9399x; 2.3273x over previous
//
#include <hip/hip_runtime.h>
#include <hip/hip_bf16.h>

typedef __bf16 bf16_t;
typedef bf16_t bf16x8 __attribute__((ext_vector_type(8)));
typedef bf16_t bf16x4 __attribute__((ext_vector_type(4)));
typedef float f32x4 __attribute__((ext_vector_type(4)));

#define SEQ 4096
#define BSZ 32
#define T_TOK 64
#define PROWS 66          // panel rows: tokens t0-1 .. t0+64
#define LSTR 264          // row stride elems (528 B)

// LDS: three 66x264 bf16 panels, aliased across phases:
//   panel0: hbf (P1)   -> S   (P2 input)
//   panel1: A   (P1out) -> AGG (P2out/P3in)
//   panel2: B   (P1out) -> HN  (P3out/P4in)
#define OFF_HBF 0
#define OFF_A   (PROWS * LSTR)
#define OFF_B   (2 * PROWS * LSTR)
#define SMEM_ELEMS (3 * PROWS * LSTR)
#define SMEM_BYTES (SMEM_ELEMS * 2)     // 104544 B -> 1 block/CU

// frag-linear weight bases (elems). Frag (nt,ks) = 512 elems = 64 lanes x 16B,
// lane l (r=l&15,kg=l>>4) elem e -> W^T[nt*16+r][ks*32+kg*8+e]
#define W1F 0           // [w1a|w1b]: 32 nt
#define NAF 131072      // nw1a: 16 nt
#define W2F 196608      // ew2
#define NBF 262144      // nw1b
#define N2F 327680      // nw2
#define WS_ELEMS 393216

#define BAR() asm volatile("s_waitcnt lgkmcnt(0)\n\ts_barrier" ::: "memory")

// ---- prepass: f32 weights -> bf16 frag-linear in ws ----
__global__ void wprep(const float* __restrict__ ew1, const float* __restrict__ ew2,
                      const float* __restrict__ nw1, const float* __restrict__ nw2,
                      bf16_t* __restrict__ wsw) {
    int idx = blockIdx.x * 256 + threadIdx.x;
    int frag = idx >> 9, o = idx & 511;
    int l = o >> 3, e = o & 7;
    int r = l & 15, kg = l >> 4;
    float v;
    if (frag < 256) {                       // [w1a|w1b]
        int nt = frag >> 3, ks = frag & 7;
        int k = ks * 32 + kg * 8 + e;
        int n = nt * 16 + r;
        v = (nt < 16) ? ew1[k * 256 + n] : ew1[(256 + k) * 256 + (n - 256)];
    } else {
        int f = frag - 256;
        int m = f >> 7;                     // 0=nw1a 1=ew2 2=nw1b 3=nw2
        int fl = f & 127;
        int nt = fl >> 3, ks = fl & 7;
        int k = ks * 32 + kg * 8 + e;
        int n = nt * 16 + r;
        const float* src = (m == 0) ? (nw1 + k * 256)
                         : (m == 1) ? (ew2 + k * 256)
                         : (m == 2) ? (nw1 + (256 + k) * 256)
                         :            (nw2 + k * 256);
        v = src[n];
    }
    wsw[idx] = (bf16_t)v;
}

// weight frag load: contiguous 1KB per wave, coalesced
#define WFRAG(base, nt, ks) \
    (*(const bf16x8*)(wsw + (base) + (((nt) * 8 + (ks)) << 9) + (lane << 3)))
// activation (B-operand) frag read from LDS panel
#define AFRAG(off, rbase, ks) \
    (*(const bf16x8*)(sm + (off) + ((rbase) + c) * LSTR + (kg << 3) + ((ks) << 5)))

__launch_bounds__(512, 2)
__global__ void gnl_kernel(const float* __restrict__ h, const float* __restrict__ mask,
                           const float* __restrict__ eb1, const float* __restrict__ eb2,
                           const float* __restrict__ nb1, const float* __restrict__ nb2,
                           const bf16_t* __restrict__ wsw, float* __restrict__ out) {
    extern __shared__ bf16_t sm[];

    const int tid   = threadIdx.x;
    const int lane  = tid & 63;
    const int w     = tid >> 6;            // wave 0..7
    const int batch = blockIdx.x >> 6;
    const int tile  = blockIdx.x & 63;
    const int t0    = tile * T_TOK;
    const long baseTok = (long)batch * SEQ;

    const int c   = lane & 15;             // token col (C col / B col) & weight row
    const int kg  = lane >> 4;             // k-group
    const int crb = kg << 2;               // C feature base {0,4,8,12}

    const int n0a = w * 16;                // wave's n-stripe cols (nt=w and nt=w+8)
    const int n0b = (w + 8) * 16;

    // ---------- stage h -> hbf (bf16, zero-padded rows) ----------
    for (int cc = tid; cc < PROWS * 32; cc += 512) {
        int r = cc >> 5;
        int fc = (cc & 31) << 3;
        int t = t0 - 1 + r;
        bf16x8 vals;
        if (t >= 0 && t < SEQ) {
            const float* src = h + (((long)(baseTok + t)) << 8) + fc;
            float4 x0 = ((const float4*)src)[0];
            float4 x1 = ((const float4*)src)[1];
            vals[0] = (bf16_t)x0.x; vals[1] = (bf16_t)x0.y;
            vals[2] = (bf16_t)x0.z; vals[3] = (bf16_t)x0.w;
            vals[4] = (bf16_t)x1.x; vals[5] = (bf16_t)x1.y;
            vals[6] = (bf16_t)x1.z; vals[7] = (bf16_t)x1.w;
        } else {
#pragma unroll
            for (int j = 0; j < 8; ++j) vals[j] = (bf16_t)0.0f;
        }
        *(bf16x8*)(sm + OFF_HBF + r * LSTR + fc) = vals;
    }
    BAR();

    // ---------- Phase 1a: A,B panels = hbf @ [w1a|w1b] ----------
    // wave stripe: pair0 = nt {w, w+8} (A panel), pair1 = nt {w+16, w+24} (B panel)
#pragma unroll
    for (int p = 0; p < 2; ++p) {
        bf16x8 wa[8], wb[8];
#pragma unroll
        for (int ks = 0; ks < 8; ++ks) {
            wa[ks] = WFRAG(W1F, w + p * 16, ks);
            wb[ks] = WFRAG(W1F, w + p * 16 + 8, ks);
        }
        int poff = p ? OFF_B : OFF_A;
#pragma unroll
        for (int mt = 0; mt < 5; ++mt) {
            bf16x8 hf[8];
#pragma unroll
            for (int ks = 0; ks < 8; ++ks) hf[ks] = AFRAG(OFF_HBF, mt * 16, ks);
            f32x4 aA = {0.f, 0.f, 0.f, 0.f}, aB = {0.f, 0.f, 0.f, 0.f};
            __builtin_amdgcn_s_setprio(1);
#pragma unroll
            for (int ks = 0; ks < 8; ++ks)
                aA = __builtin_amdgcn_mfma_f32_16x16x32_bf16(wa[ks], hf[ks], aA, 0, 0, 0);
#pragma unroll
            for (int ks = 0; ks < 8; ++ks)
                aB = __builtin_amdgcn_mfma_f32_16x16x32_bf16(wb[ks], hf[ks], aB, 0, 0, 0);
            __builtin_amdgcn_s_setprio(0);
            int row = mt * 16 + c;
            if (row < PROWS) {
                bf16x4 pA, pB;
#pragma unroll
                for (int j = 0; j < 4; ++j) { pA[j] = (bf16_t)aA[j]; pB[j] = (bf16_t)aB[j]; }
                *(bf16x4*)(sm + poff + row * LSTR + n0a + crb) = pA;
                *(bf16x4*)(sm + poff + row * LSTR + n0b + crb) = pB;
            }
        }
    }

    // ---------- Phase 1b: HA = h @ nw1a  (kept in f32 registers to P3) ----------
    f32x4 ha[4][2];
    {
        bf16x8 na[8], nb8[8];
#pragma unroll
        for (int ks = 0; ks < 8; ++ks) {
            na[ks]  = WFRAG(NAF, w, ks);
            nb8[ks] = WFRAG(NAF, w + 8, ks);
        }
#pragma unroll
        for (int tm = 0; tm < 4; ++tm) {
            bf16x8 hf[8];
#pragma unroll
            for (int ks = 0; ks < 8; ++ks) hf[ks] = AFRAG(OFF_HBF, 1 + tm * 16, ks);
            f32x4 a0 = {0.f, 0.f, 0.f, 0.f}, a1 = {0.f, 0.f, 0.f, 0.f};
            __builtin_amdgcn_s_setprio(1);
#pragma unroll
            for (int ks = 0; ks < 8; ++ks)
                a0 = __builtin_amdgcn_mfma_f32_16x16x32_bf16(na[ks], hf[ks], a0, 0, 0, 0);
#pragma unroll
            for (int ks = 0; ks < 8; ++ks)
                a1 = __builtin_amdgcn_mfma_f32_16x16x32_bf16(nb8[ks], hf[ks], a1, 0, 0, 0);
            __builtin_amdgcn_s_setprio(0);
            ha[tm][0] = a0; ha[tm][1] = a1;
        }
    }

    // prefetch P2 weights (w2) before barrier — stays in flight (no vmcnt drain)
    bf16x8 w2a[8], w2b[8];
#pragma unroll
    for (int ks = 0; ks < 8; ++ks) {
        w2a[ks] = WFRAG(W2F, w, ks);
        w2b[ks] = WFRAG(W2F, w + 8, ks);
    }
    BAR();

    // ---------- S build: S[i] = bl*relu(A[i-1]+B[i]+b1) + br*relu(A[i+1]+B[i]+b1) ----------
    // panel rows: token i -> A row i+1, so reads A rows i, i+2 and B row i+1.
    // S written into panel0 (hbf dead), rows = token index.
#pragma unroll
    for (int it = 0; it < 4; ++it) {
        int cc = tid + it * 512;               // 64*32 = 2048 exactly
        int i = cc >> 5;
        int fc = (cc & 31) << 3;
        float bl = (t0 + i >= 1) ? 1.f : 0.f;
        float br = (t0 + i <= SEQ - 2) ? 1.f : 0.f;
        bf16x8 aL = *(const bf16x8*)(sm + OFF_A + i * LSTR + fc);
        bf16x8 aR = *(const bf16x8*)(sm + OFF_A + (i + 2) * LSTR + fc);
        bf16x8 bC = *(const bf16x8*)(sm + OFF_B + (i + 1) * LSTR + fc);
        float4 b1a = *(const float4*)(eb1 + fc);
        float4 b1b = *(const float4*)(eb1 + fc + 4);
        bf16x8 sv;
#pragma unroll
        for (int j = 0; j < 8; ++j) {
            float b1f = (j < 4) ? ((const float*)&b1a)[j] : ((const float*)&b1b)[j - 4];
            float x = (float)bC[j] + b1f;
            float l = fmaxf((float)aL[j] + x, 0.f) * bl;
            float r = fmaxf((float)aR[j] + x, 0.f) * br;
            sv[j] = (bf16_t)(l + r);
        }
        *(bf16x8*)(sm + OFF_HBF + i * LSTR + fc) = sv;
    }
    BAR();

    // ---------- Phase 2: AGG = S @ w2 + cnt*b2  -> panel1 (A dead) ----------
    {
        float4 b2a = *(const float4*)(eb2 + n0a + crb);
        float4 b2b = *(const float4*)(eb2 + n0b + crb);
#pragma unroll
        for (int mt = 0; mt < 4; ++mt) {
            bf16x8 sf[8];
#pragma unroll
            for (int ks = 0; ks < 8; ++ks) sf[ks] = AFRAG(OFF_HBF, mt * 16, ks);
            f32x4 g0 = {0.f, 0.f, 0.f, 0.f}, g1 = {0.f, 0.f, 0.f, 0.f};
            __builtin_amdgcn_s_setprio(1);
#pragma unroll
            for (int ks = 0; ks < 8; ++ks)
                g0 = __builtin_amdgcn_mfma_f32_16x16x32_bf16(w2a[ks], sf[ks], g0, 0, 0, 0);
#pragma unroll
            for (int ks = 0; ks < 8; ++ks)
                g1 = __builtin_amdgcn_mfma_f32_16x16x32_bf16(w2b[ks], sf[ks], g1, 0, 0, 0);
            __builtin_amdgcn_s_setprio(0);
            int i = mt * 16 + c;
            float cnt = ((t0 + i >= 1) ? 1.f : 0.f) + ((t0 + i <= SEQ - 2) ? 1.f : 0.f);
            bf16x4 p0, p1;
#pragma unroll
            for (int j = 0; j < 4; ++j) {
                p0[j] = (bf16_t)(g0[j] + cnt * ((const float*)&b2a)[j]);
                p1[j] = (bf16_t)(g1[j] + cnt * ((const float*)&b2b)[j]);
            }
            *(bf16x4*)(sm + OFF_A + i * LSTR + n0a + crb) = p0;
            *(bf16x4*)(sm + OFF_A + i * LSTR + n0b + crb) = p1;
        }
    }
    // prefetch P3 weights (nw1b)
    bf16x8 nba[8], nbb[8];
#pragma unroll
    for (int ks = 0; ks < 8; ++ks) {
        nba[ks] = WFRAG(NBF, w, ks);
        nbb[ks] = WFRAG(NBF, w + 8, ks);
    }
    BAR();

    // ---------- Phase 3: HN = relu(HA + AGG @ nw1b + nb1) -> panel2 (B dead) ----------
    {
        float4 n1a = *(const float4*)(nb1 + n0a + crb);
        float4 n1b = *(const float4*)(nb1 + n0b + crb);
#pragma unroll
        for (int tm = 0; tm < 4; ++tm) {
            bf16x8 gf[8];
#pragma unroll
            for (int ks = 0; ks < 8; ++ks) gf[ks] = AFRAG(OFF_A, tm * 16, ks);
            f32x4 a0 = ha[tm][0], a1 = ha[tm][1];
            __builtin_amdgcn_s_setprio(1);
#pragma unroll
            for (int ks = 0; ks < 8; ++ks)
                a0 = __builtin_amdgcn_mfma_f32_16x16x32_bf16(nba[ks], gf[ks], a0, 0, 0, 0);
#pragma unroll
            for (int ks = 0; ks < 8; ++ks)
                a1 = __builtin_amdgcn_mfma_f32_16x16x32_bf16(nbb[ks], gf[ks], a1, 0, 0, 0);
            __builtin_amdgcn_s_setprio(0);
            bf16x4 p0, p1;
#pragma unroll
            for (int j = 0; j < 4; ++j) {
                p0[j] = (bf16_t)fmaxf(a0[j] + ((const float*)&n1a)[j], 0.f);
                p1[j] = (bf16_t)fmaxf(a1[j] + ((const float*)&n1b)[j], 0.f);
            }
            int i = tm * 16 + c;
            *(bf16x4*)(sm + OFF_B + i * LSTR + n0a + crb) = p0;
            *(bf16x4*)(sm + OFF_B + i * LSTR + n0b + crb) = p1;
        }
    }
    // prefetch P4 weights (nw2)
    bf16x8 n2a[8], n2b[8];
#pragma unroll
    for (int ks = 0; ks < 8; ++ks) {
        n2a[ks] = WFRAG(N2F, w, ks);
        n2b[ks] = WFRAG(N2F, w + 8, ks);
    }
    BAR();

    // ---------- Phase 4: out = h + mask * (HN @ nw2 + nb2) ----------
    {
        float4 v2a = *(const float4*)(nb2 + n0a + crb);
        float4 v2b = *(const float4*)(nb2 + n0b + crb);
#pragma unroll
        for (int tm = 0; tm < 4; ++tm) {
            bf16x8 hnf[8];
#pragma unroll
            for (int ks = 0; ks < 8; ++ks) hnf[ks] = AFRAG(OFF_B, tm * 16, ks);
            f32x4 a0 = {0.f, 0.f, 0.f, 0.f}, a1 = {0.f, 0.f, 0.f, 0.f};
            __builtin_amdgcn_s_setprio(1);
#pragma unroll
            for (int ks = 0; ks < 8; ++ks)
                a0 = __builtin_amdgcn_mfma_f32_16x16x32_bf16(n2a[ks], hnf[ks], a0, 0, 0, 0);
#pragma unroll
            for (int ks = 0; ks < 8; ++ks)
                a1 = __builtin_amdgcn_mfma_f32_16x16x32_bf16(n2b[ks], hnf[ks], a1, 0, 0, 0);
            __builtin_amdgcn_s_setprio(0);
            long t = baseTok + t0 + tm * 16 + c;
            float m = mask[t];
            long g0 = (t << 8) + n0a + crb;
            long g1 = (t << 8) + n0b + crb;
            float4 h0 = *(const float4*)(h + g0);
            float4 h1 = *(const float4*)(h + g1);
            float4 o0, o1;
            o0.x = h0.x + m * (a0[0] + v2a.x);
            o0.y = h0.y + m * (a0[1] + v2a.y);
            o0.z = h0.z + m * (a0[2] + v2a.z);
            o0.w = h0.w + m * (a0[3] + v2a.w);
            o1.x = h1.x + m * (a1[0] + v2b.x);
            o1.y = h1.y + m * (a1[1] + v2b.y);
            o1.z = h1.z + m * (a1[2] + v2b.z);
            o1.w = h1.w + m * (a1[3] + v2b.w);
            *(float4*)(out + g0) = o0;
            *(float4*)(out + g1) = o1;
        }
    }
}

extern "C" void kernel_launch(void* const* d_in, const int* in_sizes, int n_in,
                              void* d_out, int out_size, void* d_ws, size_t ws_size,
                              hipStream_t stream) {
    const float* h    = (const float*)d_in[0];
    const float* mask = (const float*)d_in[1];
    const float* ew1  = (const float*)d_in[2];
    const float* eb1  = (const float*)d_in[3];
    const float* ew2  = (const float*)d_in[4];
    const float* eb2  = (const float*)d_in[5];
    const float* nw1  = (const float*)d_in[6];
    const float* nb1  = (const float*)d_in[7];
    const float* nw2  = (const float*)d_in[8];
    const float* nb2  = (const float*)d_in[9];
    float* out   = (float*)d_out;
    bf16_t* wsw  = (bf16_t*)d_ws;

    wprep<<<WS_ELEMS / 256, 256, 0, stream>>>(ew1, ew2, nw1, nw2, wsw);

    hipFuncSetAttribute(reinterpret_cast<const void*>(gnl_kernel),
                        hipFuncAttributeMaxDynamicSharedMemorySize, SMEM_BYTES);

    gnl_kernel<<<BSZ * (SEQ / T_TOK), 512, SMEM_BYTES, stream>>>(
        h, mask, eb1, eb2, nb1, nb2, wsw, out);
}

// Round 6
// 169.521 us; speedup vs baseline: 3.9785x; 1.0098x over previous
//
#include <hip/hip_runtime.h>
#include <hip/hip_bf16.h>

typedef __bf16 bf16_t;
typedef bf16_t bf16x8 __attribute__((ext_vector_type(8)));
typedef bf16_t bf16x4 __attribute__((ext_vector_type(4)));
typedef float f32x4 __attribute__((ext_vector_type(4)));

#define SEQ 4096
#define BSZ 32
#define T_TOK 64
#define PROWS 66          // panel rows: tokens t0-1 .. t0+64
#define LSTR 264          // row stride elems (528 B)

// LDS: three 66x264 bf16 panels, aliased:
//   P0: hbf (stage,P1a,P1b) -> S (written by S-pass, read by P3')
//   P1: A (P1a out, S-pass in) -> HN (P3' out, P4 in)
//   P2: B (P1a out, S-pass in)
#define OFF_P0 0
#define OFF_P1 (PROWS * LSTR)
#define OFF_P2 (2 * PROWS * LSTR)
#define SMEM_ELEMS (3 * PROWS * LSTR)
#define SMEM_BYTES (SMEM_ELEMS * 2)     // 104544 B -> 1 block/CU

// frag-linear weight bases (bf16 elems). Frag (nt,ks) = 512 elems;
// lane l (r=l&15,kg=l>>4), elem e -> W^T[nt*16+r][ks*32+kg*8+e]
#define W1F 0           // [w1a|w1b]: 32 nt
#define NAF 131072      // nw1a: 16 nt
#define WBF 196608      // W2B = ew2 @ nw1b (fused phase-2): 16 nt
#define N2F 262144      // nw2: 16 nt
#define B2N 327680      // 256 f32: eb2 @ nw1b

#define BAR() asm volatile("s_waitcnt lgkmcnt(0)\n\ts_barrier" ::: "memory")

// ---- prepass 1: direct transposes -> frag-linear bf16 ----
__global__ void wprep(const float* __restrict__ ew1, const float* __restrict__ nw1,
                      const float* __restrict__ nw2, bf16_t* __restrict__ wsw) {
    int idx = blockIdx.x * 256 + threadIdx.x;      // 0..262143
    int region, rel, outbase;
    if (idx < 131072)      { region = 0; rel = idx;          outbase = W1F; }
    else if (idx < 196608) { region = 1; rel = idx - 131072; outbase = NAF; }
    else                   { region = 2; rel = idx - 196608; outbase = N2F; }
    int f = rel >> 9, o = rel & 511;
    int l = o >> 3, e = o & 7;
    int r = l & 15, kg = l >> 4;
    int nt = f >> 3, ks = f & 7;
    int k = ks * 32 + kg * 8 + e;
    int n = nt * 16 + r;
    float v;
    if (region == 0)
        v = (nt < 16) ? ew1[k * 256 + n] : ew1[(256 + k) * 256 + (n - 256)];
    else if (region == 1)
        v = nw1[k * 256 + n];
    else
        v = nw2[k * 256 + n];
    wsw[outbase + rel] = (bf16_t)v;
}

// ---- prepass 2: W2B = ew2 @ nw1b (frag-linear), b2n = eb2 @ nw1b ----
__global__ void wprep2(const float* __restrict__ ew2, const float* __restrict__ eb2,
                       const float* __restrict__ nw1, bf16_t* __restrict__ wsw) {
    int k = blockIdx.x;
    int n = threadIdx.x;
    if (k < 256) {
        float acc = 0.f;
        for (int j = 0; j < 256; ++j)
            acc += ew2[k * 256 + j] * nw1[(256 + j) * 256 + n];
        int ks = k >> 5, kg = (k >> 3) & 3, e = k & 7;
        int nt = n >> 4, r = n & 15;
        wsw[WBF + ((nt * 8 + ks) << 9) + ((kg * 16 + r) << 3) + e] = (bf16_t)acc;
    } else {
        float acc = 0.f;
        for (int j = 0; j < 256; ++j)
            acc += eb2[j] * nw1[(256 + j) * 256 + n];
        ((float*)(wsw + B2N))[n] = acc;
    }
}

__launch_bounds__(512, 2)
__global__ void gnl_kernel(const float* __restrict__ h, const float* __restrict__ mask,
                           const float* __restrict__ eb1, const float* __restrict__ nb1,
                           const float* __restrict__ nb2,
                           const bf16_t* __restrict__ wsw, float* __restrict__ out) {
    extern __shared__ bf16_t sm[];

    const int tid   = threadIdx.x;
    const int lane  = tid & 63;
    const int w     = tid >> 6;            // wave 0..7
    const int batch = blockIdx.x >> 6;
    const int tile  = blockIdx.x & 63;
    const int t0    = tile * T_TOK;
    const long baseTok = (long)batch * SEQ;

    const int c   = lane & 15;             // token col / weight row
    const int kg  = lane >> 4;
    const int crb = kg << 2;               // C feature base {0,4,8,12}
    const int n0a = w * 16;
    const int n0b = (w + 8) * 16;

    auto loadw = [&](bf16x8 (&f)[8], int base, int nt) {
#pragma unroll
        for (int ks = 0; ks < 8; ++ks)
            f[ks] = *(const bf16x8*)(wsw + base + ((nt * 8 + ks) << 9) + (lane << 3));
    };
    auto loada = [&](bf16x8 (&f)[8], int poff, int rbase) {
        const bf16_t* p = sm + poff + (rbase + c) * LSTR + (kg << 3);
#pragma unroll
        for (int ks = 0; ks < 8; ++ks) f[ks] = *(const bf16x8*)(p + (ks << 5));
    };
    auto mfma2 = [&](bf16x8 (&f)[8], bf16x8 (&wa)[8], bf16x8 (&wb)[8],
                     f32x4& a0, f32x4& a1) {
        __builtin_amdgcn_s_setprio(1);
#pragma unroll
        for (int ks = 0; ks < 8; ++ks) {      // interleaved dual chains
            a0 = __builtin_amdgcn_mfma_f32_16x16x32_bf16(wa[ks], f[ks], a0, 0, 0, 0);
            a1 = __builtin_amdgcn_mfma_f32_16x16x32_bf16(wb[ks], f[ks], a1, 0, 0, 0);
        }
        __builtin_amdgcn_s_setprio(0);
    };

    // ---------- stage h -> P0 (bf16, zero-padded boundary rows) ----------
    for (int cc = tid; cc < PROWS * 32; cc += 512) {
        int r = cc >> 5;
        int fc = (cc & 31) << 3;
        int t = t0 - 1 + r;
        bf16x8 vals;
        if (t >= 0 && t < SEQ) {
            const float* src = h + (((long)(baseTok + t)) << 8) + fc;
            float4 x0 = ((const float4*)src)[0];
            float4 x1 = ((const float4*)src)[1];
            vals[0] = (bf16_t)x0.x; vals[1] = (bf16_t)x0.y;
            vals[2] = (bf16_t)x0.z; vals[3] = (bf16_t)x0.w;
            vals[4] = (bf16_t)x1.x; vals[5] = (bf16_t)x1.y;
            vals[6] = (bf16_t)x1.z; vals[7] = (bf16_t)x1.w;
        } else {
#pragma unroll
            for (int j = 0; j < 8; ++j) vals[j] = (bf16_t)0.0f;
        }
        *(bf16x8*)(sm + OFF_P0 + r * LSTR + fc) = vals;
    }
    BAR();

    // ---------- Phase 1a: A,B panels = hbf @ [w1a|w1b] ----------
#pragma unroll
    for (int p = 0; p < 2; ++p) {
        bf16x8 wa[8], wb[8];
        loadw(wa, W1F, w + p * 16);
        loadw(wb, W1F, w + p * 16 + 8);
        int poff = p ? OFF_P2 : OFF_P1;
        bf16x8 fA[8], fB[8];
        loada(fA, OFF_P0, 0);
#pragma unroll
        for (int mt = 0; mt < 5; ++mt) {
            bf16x8 (&cur)[8] = (mt & 1) ? fB : fA;
            bf16x8 (&nxt)[8] = (mt & 1) ? fA : fB;
            if (mt < 4) loada(nxt, OFF_P0, (mt + 1) * 16);   // 1-ahead prefetch
            f32x4 aA = {0.f, 0.f, 0.f, 0.f}, aB = {0.f, 0.f, 0.f, 0.f};
            mfma2(cur, wa, wb, aA, aB);
            int row = mt * 16 + c;
            if (row < PROWS) {
                bf16x4 pA, pB;
#pragma unroll
                for (int j = 0; j < 4; ++j) { pA[j] = (bf16_t)aA[j]; pB[j] = (bf16_t)aB[j]; }
                *(bf16x4*)(sm + poff + row * LSTR + n0a + crb) = pA;
                *(bf16x4*)(sm + poff + row * LSTR + n0b + crb) = pB;
            }
        }
    }

    // ---------- Phase 1b: HA = h @ nw1a (f32 registers, consumed in P3') ----------
    f32x4 ha[4][2];
    {
        bf16x8 na[8], nb8[8];
        loadw(na, NAF, w);
        loadw(nb8, NAF, w + 8);
        bf16x8 fA[8], fB[8];
        loada(fA, OFF_P0, 1);
#pragma unroll
        for (int tm = 0; tm < 4; ++tm) {
            bf16x8 (&cur)[8] = (tm & 1) ? fB : fA;
            bf16x8 (&nxt)[8] = (tm & 1) ? fA : fB;
            if (tm < 3) loada(nxt, OFF_P0, tm * 16 + 17);
            f32x4 a0 = {0.f, 0.f, 0.f, 0.f}, a1 = {0.f, 0.f, 0.f, 0.f};
            mfma2(cur, na, nb8, a0, a1);
            ha[tm][0] = a0; ha[tm][1] = a1;
        }
    }

    // prefetch P3' weights (W2B) — vmcnt not drained by BAR, stays in flight
    bf16x8 wba[8], wbb[8];
    loadw(wba, WBF, w);
    loadw(wbb, WBF, w + 8);
    BAR();

    // ---------- S pass: S[i] = bl*relu(A[i]+B[i+1]+b1) + br*relu(A[i+2]+B[i+1]+b1) ----------
    // writes S into P0 (hbf dead), rows = token index 0..63
#pragma unroll
    for (int it = 0; it < 4; ++it) {
        int cc = tid + it * 512;               // 64*32 = 2048 exactly
        int i = cc >> 5;
        int fc = (cc & 31) << 3;
        float bl = (t0 + i >= 1) ? 1.f : 0.f;
        float br = (t0 + i <= SEQ - 2) ? 1.f : 0.f;
        bf16x8 aL = *(const bf16x8*)(sm + OFF_P1 + i * LSTR + fc);
        bf16x8 aR = *(const bf16x8*)(sm + OFF_P1 + (i + 2) * LSTR + fc);
        bf16x8 bC = *(const bf16x8*)(sm + OFF_P2 + (i + 1) * LSTR + fc);
        float4 b1a = *(const float4*)(eb1 + fc);
        float4 b1b = *(const float4*)(eb1 + fc + 4);
        bf16x8 sv;
#pragma unroll
        for (int j = 0; j < 8; ++j) {
            float b1f = (j < 4) ? ((const float*)&b1a)[j] : ((const float*)&b1b)[j - 4];
            float x = (float)bC[j] + b1f;
            float l = fmaxf((float)aL[j] + x, 0.f) * bl;
            float r = fmaxf((float)aR[j] + x, 0.f) * br;
            sv[j] = (bf16_t)(l + r);
        }
        *(bf16x8*)(sm + OFF_P0 + i * LSTR + fc) = sv;
    }
    BAR();

    // ---------- Phase 3': HN = relu(HA + S @ W2B + nb1 + cnt*b2n) -> P1 ----------
    {
        float4 n1a = *(const float4*)(nb1 + n0a + crb);
        float4 n1b = *(const float4*)(nb1 + n0b + crb);
        const float* b2n = (const float*)(wsw + B2N);
        float4 c2a = *(const float4*)(b2n + n0a + crb);
        float4 c2b = *(const float4*)(b2n + n0b + crb);
        bf16x8 fA[8], fB[8];
        loada(fA, OFF_P0, 0);
#pragma unroll
        for (int tm = 0; tm < 4; ++tm) {
            bf16x8 (&cur)[8] = (tm & 1) ? fB : fA;
            bf16x8 (&nxt)[8] = (tm & 1) ? fA : fB;
            if (tm < 3) loada(nxt, OFF_P0, (tm + 1) * 16);
            f32x4 a0 = ha[tm][0], a1 = ha[tm][1];
            mfma2(cur, wba, wbb, a0, a1);
            int row = tm * 16 + c;
            int t = t0 + row;
            float cnt = ((t >= 1) ? 1.f : 0.f) + ((t <= SEQ - 2) ? 1.f : 0.f);
            bf16x4 p0, p1;
#pragma unroll
            for (int j = 0; j < 4; ++j) {
                p0[j] = (bf16_t)fmaxf(a0[j] + ((const float*)&n1a)[j] + cnt * ((const float*)&c2a)[j], 0.f);
                p1[j] = (bf16_t)fmaxf(a1[j] + ((const float*)&n1b)[j] + cnt * ((const float*)&c2b)[j], 0.f);
            }
            *(bf16x4*)(sm + OFF_P1 + row * LSTR + n0a + crb) = p0;
            *(bf16x4*)(sm + OFF_P1 + row * LSTR + n0b + crb) = p1;
        }
    }
    // prefetch P4 weights (nw2) — wba/wbb dead, register peak stays bounded
    bf16x8 n2a[8], n2b[8];
    loadw(n2a, N2F, w);
    loadw(n2b, N2F, w + 8);
    BAR();

    // ---------- Phase 4: out = h + mask * (HN @ nw2 + nb2) ----------
    {
        float4 v2a = *(const float4*)(nb2 + n0a + crb);
        float4 v2b = *(const float4*)(nb2 + n0b + crb);
        bf16x8 fA[8], fB[8];
        loada(fA, OFF_P1, 0);
#pragma unroll
        for (int tm = 0; tm < 4; ++tm) {
            long t = baseTok + t0 + tm * 16 + c;
            float m = mask[t];                       // issued early,
            long g0 = (t << 8) + n0a + crb;
            long g1 = (t << 8) + n0b + crb;
            float4 h0 = *(const float4*)(h + g0);    // in flight under MFMA
            float4 h1 = *(const float4*)(h + g1);
            bf16x8 (&cur)[8] = (tm & 1) ? fB : fA;
            bf16x8 (&nxt)[8] = (tm & 1) ? fA : fB;
            if (tm < 3) loada(nxt, OFF_P1, (tm + 1) * 16);
            f32x4 a0 = {0.f, 0.f, 0.f, 0.f}, a1 = {0.f, 0.f, 0.f, 0.f};
            mfma2(cur, n2a, n2b, a0, a1);
            float4 o0, o1;
            o0.x = h0.x + m * (a0[0] + v2a.x);
            o0.y = h0.y + m * (a0[1] + v2a.y);
            o0.z = h0.z + m * (a0[2] + v2a.z);
            o0.w = h0.w + m * (a0[3] + v2a.w);
            o1.x = h1.x + m * (a1[0] + v2b.x);
            o1.y = h1.y + m * (a1[1] + v2b.y);
            o1.z = h1.z + m * (a1[2] + v2b.z);
            o1.w = h1.w + m * (a1[3] + v2b.w);
            *(float4*)(out + g0) = o0;
            *(float4*)(out + g1) = o1;
        }
    }
}

extern "C" void kernel_launch(void* const* d_in, const int* in_sizes, int n_in,
                              void* d_out, int out_size, void* d_ws, size_t ws_size,
                              hipStream_t stream) {
    const float* h    = (const float*)d_in[0];
    const float* mask = (const float*)d_in[1];
    const float* ew1  = (const float*)d_in[2];
    const float* eb1  = (const float*)d_in[3];
    const float* ew2  = (const float*)d_in[4];
    const float* eb2  = (const float*)d_in[5];
    const float* nw1  = (const float*)d_in[6];
    const float* nb1  = (const float*)d_in[7];
    const float* nw2  = (const float*)d_in[8];
    const float* nb2  = (const float*)d_in[9];
    float* out   = (float*)d_out;
    bf16_t* wsw  = (bf16_t*)d_ws;

    wprep<<<1024, 256, 0, stream>>>(ew1, nw1, nw2, wsw);
    wprep2<<<257, 256, 0, stream>>>(ew2, eb2, nw1, wsw);

    hipFuncSetAttribute(reinterpret_cast<const void*>(gnl_kernel),
                        hipFuncAttributeMaxDynamicSharedMemorySize, SMEM_BYTES);

    gnl_kernel<<<BSZ * (SEQ / T_TOK), 512, SMEM_BYTES, stream>>>(
        h, mask, eb1, nb1, nb2, wsw, out);
}